// Round 4
// baseline (919.734 us; speedup 1.0000x reference)
//
#include <hip/hip_runtime.h>
#include <math.h>

// Problem constants (static shapes per reference)
#define KP 16384
#define DP 2048
#define THRESH 0.5f
#define DECAY 0.99f
#define ROWS_PER_BLOCK 16
#define GRID_ROWS (KP / ROWS_PER_BLOCK)  // 1024 blocks of 16 waves (1 row/wave)

// ws layout:
// int  [0]  completion counter for k_dots_copy tail (zeroed by k_argmin)
// int  [1]  completion counter for k_ema tail       (zeroed by k_argmin)
// int  [2]  idxMin = argmin(usages)
// int  [3]  flag   = 1 evict, 0 ema
// f32  [4]  max_all (max of logits)
// f32  [5]  sumexp_all (ema softmax denom, exp(l - max_all))
// f32  [6]  u
// f32  [7]  zz = ||z||^2
// [8          .. 8+K)    logits
// [8+K        .. 8+2K)   zp (z . p_row)
// [8+2K       .. 8+3K)   pp (||p_row||^2)
// [8+3K       .. 8+4K)   logits2 (ema path only)
// total: (8 + 4*16384)*4 = 262176 bytes

typedef float f4 __attribute__((ext_vector_type(4)));
typedef float f2 __attribute__((ext_vector_type(2)));
typedef unsigned long long u64;

__device__ __forceinline__ float waveReduceSum(float v) {
    #pragma unroll
    for (int m = 32; m >= 1; m >>= 1) v += __shfl_xor(v, m, 64);
    return v;
}

__device__ __forceinline__ unsigned int fkey(float v) {
    // monotone float->uint key (order-preserving for all finite floats)
    unsigned int b = __float_as_uint(v);
    return (b & 0x80000000u) ? ~b : (b | 0x80000000u);
}
__device__ __forceinline__ float fkey_inv(unsigned int key) {
    unsigned int b = (key & 0x80000000u) ? (key ^ 0x80000000u) : ~key;
    return __uint_as_float(b);
}

// ---------------- Kernel 1: argmin(usages) (single block) ----------------
// shfl-butterfly min (order-safe packed keys); also zeroes the two
// completion counters used by the fused tails (ws is poisoned by harness).
__global__ __launch_bounds__(1024) void k_argmin(const float* __restrict__ usages,
                                                 float* __restrict__ W) {
    __shared__ u64 s[16];
    const int t = threadIdx.x;
    if (t == 0) { ((int*)W)[0] = 0; ((int*)W)[1] = 0; }
    u64 best = ~0ULL;
    #pragma unroll
    for (int i = 0; i < KP / 1024; i++) {
        const int j = t + i * 1024;
        u64 p = ((u64)fkey(usages[j]) << 32) | (unsigned int)j;
        if (p < best) best = p;  // min; equal key -> smaller j wins (first occurrence)
    }
    #pragma unroll
    for (int m = 32; m >= 1; m >>= 1) {
        u64 o = __shfl_xor(best, m, 64);
        if (o < best) best = o;
    }
    if ((t & 63) == 0) s[t >> 6] = best;
    __syncthreads();
    if (t < 64) {  // whole wave active; values repeat every 16 lanes
        best = s[t & 15];
        #pragma unroll
        for (int m = 8; m >= 1; m >>= 1) {
            u64 o = __shfl_xor(best, m, 64);
            if (o < best) best = o;
        }
        if (t == 0) ((int*)W)[2] = (int)(best & 0xFFFFFFFFu);
    }
}

// ---- Kernel 2: fused dots + speculative evict copy + scalar tail ----
// Memory path (R2/R3 verdicts, kept): nt loads on P (-15us, dodges the
// MALL dirty-poison eviction tax on the read path); store flavor is
// irrelevant (R1/R3 both null) -> nt stores kept. Accounting: 268MB own
// traffic + ~134MB hidden poison writeback in ~67us = ~6 TB/s real bus
// = at the achievable ceiling. This kernel's BW is done.
// NEW (R4): 1024-thr blocks (16 rows); completion-count tail -- the last
// block to finish runs k_scalar's body VERBATIM (same 1024-thread mapping,
// bit-identical reduction trees; values re-read from W are the same bits).
// Saves one launch + the full-grid drain/launch gap before the scalar work.
__global__ __launch_bounds__(1024) void k_dots_copy(const float* __restrict__ z,
                                                    const float* __restrict__ P,
                                                    const float* __restrict__ usages,
                                                    const float* __restrict__ beta,
                                                    const float* __restrict__ gamma,
                                                    const float* __restrict__ temp,
                                                    float* __restrict__ W,
                                                    float* __restrict__ out) {
    __shared__ float sf[1024];
    __shared__ float sm[16];
    __shared__ u64 sb[16];
    __shared__ int isLast;
    const int wave = threadIdx.x >> 6;
    const int lane = threadIdx.x & 63;
    const int r = blockIdx.x * ROWS_PER_BLOCK + wave;
    const int idx = ((const int*)W)[2];

    const float* prow = P + (size_t)r * DP;

    f4 v[8];
    float zp = 0.f, pp = 0.f, zz = 0.f;
    #pragma unroll
    for (int i = 0; i < 8; i++) {
        const int c = i * 256 + lane * 4;
        const f4 pv = __builtin_nontemporal_load((const f4*)(prow + c));
        const f4 zv = *(const f4*)(z + c);
        v[i] = pv;
        zp += pv.x * zv.x + pv.y * zv.y + pv.z * zv.z + pv.w * zv.w;
        pp += pv.x * pv.x + pv.y * pv.y + pv.z * pv.z + pv.w * pv.w;
        zz += zv.x * zv.x + zv.y * zv.y + zv.z * zv.z + zv.w * zv.w;
    }

    // Speculative evict-layout copy: in-row r -> out-row (r<idx ? r : r-1), row idx dropped.
    // (If the EMA branch is taken, k_ema rewrites every out row from pristine d_in.)
    if (r != idx) {
        const int ro = (r < idx) ? r : r - 1;
        float* orow = out + 3 + (size_t)ro * DP;
        if (lane == 0) __builtin_nontemporal_store(v[0].x, orow);  // element 0
        #pragma unroll
        for (int i = 0; i < 8; i++) {
            float nx = __shfl_down(v[i].x, 1);            // lane l -> lane l+1's .x
            const float bx = __shfl(v[(i + 1) & 7].x, 0); // lane 63 -> next iter, lane 0
            if (lane == 63) nx = bx;
            f4 ov;
            ov.x = v[i].y; ov.y = v[i].z; ov.z = v[i].w; ov.w = nx;
            if (i < 7 || lane < 63) {  // chunk 511 would run past the row
                __builtin_nontemporal_store(ov, (f4*)(orow + 1 + 4 * (i * 64 + lane)));
            }
        }
        if (lane == 63) {  // tail elements 2045..2047
            f2 t2; t2.x = v[7].y; t2.y = v[7].z;
            __builtin_nontemporal_store(t2, (f2*)(orow + DP - 3));
            __builtin_nontemporal_store(v[7].w, orow + DP - 1);
        }
    }

    zp = waveReduceSum(zp);
    pp = waveReduceSum(pp);
    zz = waveReduceSum(zz);
    if (lane == 0) {
        W[8 + r]          = temp[0] * zp / sqrtf(zz * pp);  // logit
        W[8 + KP + r]     = zp;
        W[8 + 2 * KP + r] = pp;
        if (r == 0) W[7] = zz;
    }

    // ---------------- completion-count gate ----------------
    __threadfence();
    __syncthreads();
    if (threadIdx.x == 0) isLast = (atomicAdd((int*)W, 1) == GRID_ROWS - 1);
    __syncthreads();
    if (!isLast) return;
    __threadfence();

    // ---------------- scalar tail (k_scalar body, t in [0,1024)) ----------------
    const int t = threadIdx.x;
    float mx_all = -INFINITY;
    u64 bestx = 0;  // packed (key<<32)|~j, argmax excluding idx
    #pragma unroll
    for (int i = 0; i < KP / 1024; i++) {
        const int j = t + i * 1024;
        const float v2 = W[8 + j];
        mx_all = fmaxf(mx_all, v2);
        if (j != idx) {
            u64 p = ((u64)fkey(v2) << 32) | (unsigned int)(~j);
            if (p > bestx) bestx = p;  // max; equal key -> larger ~j = smaller j wins
        }
    }
    #pragma unroll
    for (int m = 32; m >= 1; m >>= 1) {
        mx_all = fmaxf(mx_all, __shfl_xor(mx_all, m, 64));
        u64 o = __shfl_xor(bestx, m, 64);
        if (o > bestx) bestx = o;
    }
    if ((t & 63) == 0) { sm[t >> 6] = mx_all; sb[t >> 6] = bestx; }
    __syncthreads();
    if (t < 64) {  // whole wave active; values repeat every 16 lanes
        float m = sm[t & 15];
        u64 b = sb[t & 15];
        #pragma unroll
        for (int mk = 8; mk >= 1; mk >>= 1) {
            m = fmaxf(m, __shfl_xor(m, mk, 64));
            u64 o = __shfl_xor(b, mk, 64);
            if (o > b) b = o;
        }
        if (t == 0) { sm[0] = m; sb[0] = b; }
    }
    __syncthreads();
    mx_all = sm[0];

    const float u = 1.f / (1.f + expf(-((-mx_all - beta[0]) / gamma[0])));
    const int flag = (u >= THRESH) ? 1 : 0;  // uniform across block
    if (t == 0) {
        out[2] = u;
        ((int*)W)[3] = flag;
        W[4] = mx_all;
        W[6] = u;
    }

    if (flag) {
        // ---------- evict epilogue ----------
        const u64 bp = sb[0];
        const float mxe = fkey_inv((unsigned int)(bp >> 32));
        const int amax = (int)(~(unsigned int)(bp & 0xFFFFFFFFu));

        const float tq = temp[0];
        const float M2 = fmaxf(mxe, tq);
        float s = 0.f;
        #pragma unroll
        for (int i = 0; i < KP / 1024; i++) {
            const int j = t + i * 1024;
            if (j != idx) s += expf(W[8 + j] - M2);
        }
        sf[t] = s;
        __syncthreads();
        for (int off = 512; off >= 1; off >>= 1) {
            if (t < off) sf[t] += sf[t + off];
            __syncthreads();
        }
        if (t == 0) {
            const float total = sf[0] + expf(tq - M2);
            out[0] = logf(total);  // loss = logsumexp(l2) - max(l2); l2[label]==max
            const int label = (mxe >= tq) ? (amax < idx ? amax : amax - 1) : (KP - 1);
            out[1] = (float)label;
        }
        // new_usages = [usages[src]; 1.0] * DECAY
        float* ou = out + 3 + (size_t)KP * DP;
        #pragma unroll
        for (int i = 0; i < KP / 1024; i++) {
            const int j = t + i * 1024;
            ou[j] = (j < KP - 1) ? usages[j < idx ? j : j + 1] * DECAY : DECAY;
        }
        // new_protos last row = z
        float* orow = out + 3 + (size_t)(KP - 1) * DP;
        orow[t] = z[t];
        orow[t + 1024] = z[t + 1024];
    } else {
        // ---------- ema prep: softmax denominator ----------
        float s = 0.f;
        #pragma unroll
        for (int i = 0; i < KP / 1024; i++) s += expf(W[8 + t + i * 1024] - mx_all);
        sf[t] = s;
        __syncthreads();
        for (int off = 512; off >= 1; off >>= 1) {
            if (t < off) sf[t] += sf[t + off];
            __syncthreads();
        }
        if (t == 0) W[5] = sf[0];
    }
}

// --------- Kernel 3: EMA rewrite + loss tail (early-exits in evict case) ---------
// 1024-thr blocks, register-shuffle store path (no LDS staging), completion-count
// tail runs the old k_ema_loss body verbatim in the last block.
__global__ __launch_bounds__(1024) void k_ema(const float* __restrict__ z,
                                              const float* __restrict__ P,
                                              const float* __restrict__ usages,
                                              const float* __restrict__ temp,
                                              float* __restrict__ W,
                                              float* __restrict__ out) {
    if (((const int*)W)[3]) return;  // evict branch taken -> nothing to do
    __shared__ u64 sp[1024];
    __shared__ float sfl[1024];
    __shared__ int isLast;
    const int wave = threadIdx.x >> 6;
    const int lane = threadIdx.x & 63;
    const int r = blockIdx.x * ROWS_PER_BLOCK + wave;

    const float mx = W[4], se = W[5], u = W[6], zz = W[7];
    const float lg = W[8 + r], zp = W[8 + KP + r], pp = W[8 + 2 * KP + r];
    const float y = expf(lg - mx) / se;
    const float delta = y * (1.f - u);
    const float usg = usages[r];
    const float a = delta / (delta + usg);
    const float b = usg / (usg + delta);

    const float* prow = P + (size_t)r * DP;
    float* orow = out + 3 + (size_t)r * DP;
    f4 v[8];
    #pragma unroll
    for (int i = 0; i < 8; i++) {
        const int c = i * 256 + lane * 4;
        const f4 pv = *(const f4*)(prow + c);
        const f4 zv = *(const f4*)(z + c);
        f4 ov;
        ov.x = a * zv.x + b * pv.x;
        ov.y = a * zv.y + b * pv.y;
        ov.z = a * zv.z + b * pv.z;
        ov.w = a * zv.w + b * pv.w;
        v[i] = ov;
    }
    // same +3-shift realignment as k_dots_copy (row r -> out row r, unshifted index)
    if (lane == 0) __builtin_nontemporal_store(v[0].x, orow);
    #pragma unroll
    for (int i = 0; i < 8; i++) {
        float nx = __shfl_down(v[i].x, 1);
        const float bx = __shfl(v[(i + 1) & 7].x, 0);
        if (lane == 63) nx = bx;
        f4 ov;
        ov.x = v[i].y; ov.y = v[i].z; ov.z = v[i].w; ov.w = nx;
        if (i < 7 || lane < 63) {
            __builtin_nontemporal_store(ov, (f4*)(orow + 1 + 4 * (i * 64 + lane)));
        }
    }
    if (lane == 63) {
        f2 t2; t2.x = v[7].y; t2.y = v[7].z;
        __builtin_nontemporal_store(t2, (f2*)(orow + DP - 3));
        __builtin_nontemporal_store(v[7].w, orow + DP - 1);
    }

    if (lane == 0) {
        // logits2 analytically: new_p = a*z + b*p
        const float dzn = a * zz + b * zp;          // z . new_p
        const float n2 = a * a * zz + 2.f * a * b * zp + b * b * pp;  // ||new_p||^2
        W[8 + 3 * KP + r] = temp[0] * dzn / sqrtf(zz * n2);
        out[3 + (size_t)KP * DP + r] = (usg + delta) * DECAY;
    }

    // ---------------- completion-count gate ----------------
    __threadfence();
    __syncthreads();
    if (threadIdx.x == 0) isLast = (atomicAdd((int*)W + 1, 1) == GRID_ROWS - 1);
    __syncthreads();
    if (!isLast) return;
    __threadfence();

    // ---------------- loss tail (k_ema_loss body, t in [0,1024)) ----------------
    const int t = threadIdx.x;
    float l2[KP / 1024];
    u64 best = 0;
    #pragma unroll
    for (int i = 0; i < KP / 1024; i++) {
        const int j = t + i * 1024;
        const float vv = W[8 + 3 * KP + j];
        l2[i] = vv;
        u64 p = ((u64)fkey(vv) << 32) | (unsigned int)(~j);
        if (p > best) best = p;
    }
    sp[t] = best;
    __syncthreads();
    for (int off = 512; off >= 1; off >>= 1) {
        if (t < off) { if (sp[t + off] > sp[t]) sp[t] = sp[t + off]; }
        __syncthreads();
    }
    const u64 bp = sp[0];
    const float mxl = fkey_inv((unsigned int)(bp >> 32));
    const int label = (int)(~(unsigned int)(bp & 0xFFFFFFFFu));

    float s = 0.f;
    #pragma unroll
    for (int i = 0; i < KP / 1024; i++) s += expf(l2[i] - mxl);
    __syncthreads();
    sfl[t] = s;
    __syncthreads();
    for (int off = 512; off >= 1; off >>= 1) {
        if (t < off) sfl[t] += sfl[t + off];
        __syncthreads();
    }
    if (t == 0) {
        out[0] = logf(sfl[0]);  // l2[label] == mx
        out[1] = (float)label;
    }
}

extern "C" void kernel_launch(void* const* d_in, const int* in_sizes, int n_in,
                              void* d_out, int out_size, void* d_ws, size_t ws_size,
                              hipStream_t stream) {
    const float* z      = (const float*)d_in[0];
    const float* P      = (const float*)d_in[1];
    const float* usages = (const float*)d_in[2];
    const float* beta   = (const float*)d_in[3];
    const float* gamma  = (const float*)d_in[4];
    const float* temp   = (const float*)d_in[5];
    float* out = (float*)d_out;
    float* W   = (float*)d_ws;  // needs (8 + 4*KP)*4 = 262176 bytes

    k_argmin<<<1, 1024, 0, stream>>>(usages, W);
    k_dots_copy<<<GRID_ROWS, 1024, 0, stream>>>(z, P, usages, beta, gamma, temp, W, out);
    k_ema<<<GRID_ROWS, 1024, 0, stream>>>(z, P, usages, temp, W, out);
}

// Round 5
// 288.331 us; speedup vs baseline: 3.1899x; 3.1899x over previous
//
#include <hip/hip_runtime.h>
#include <math.h>

// Problem constants (static shapes per reference)
#define KP 16384
#define DP 2048
#define THRESH 0.5f
#define DECAY 0.99f
#define GRID_DOTS (KP / 4)  // 4096 blocks x 256 thr (4 waves, 1 row/wave) -- R3 shape

// ws layout:
// int  [0]  completion counter, k_dots_copy gate (zeroed by k_argmin each call)
// int  [1]  completion counter, k_ema gate       (zeroed by k_argmin each call)
// int  [2]  idxMin = argmin(usages)
// int  [3]  flag   = 1 evict, 0 ema
// f32  [4]  max_all; [5] sumexp_all; [6] u; [7] zz
// [8..8+K) logits (sc1 device-coherent stores -- read by fused tail)
// [8+K..8+2K) zp   [8+2K..8+3K) pp   [8+3K..8+4K) logits2 (sc1, read by ema tail)
// total: (8 + 4*16384)*4 = 262176 bytes
//
// R4 lesson (742us regression): __threadfence() on gfx950 = s_waitcnt + buffer_wbl2
// (full per-XCD L2 writeback, since XCD L2s are non-coherent) -- 1024 of those
// serialized the machine. Fence-free protocol instead: the ONLY cross-block data
// the tail consumes (logits) is stored with sc1 write-through (__hip_atomic_store
// relaxed/agent), drained per-wave with s_waitcnt vmcnt(0), gated by one relaxed
// atomicAdd, and read back with sc1 loads. No cache maintenance instructions.

typedef float f4 __attribute__((ext_vector_type(4)));
typedef float f2 __attribute__((ext_vector_type(2)));
typedef unsigned long long u64;

__device__ __forceinline__ float waveReduceSum(float v) {
    #pragma unroll
    for (int m = 32; m >= 1; m >>= 1) v += __shfl_xor(v, m, 64);
    return v;
}

__device__ __forceinline__ unsigned int fkey(float v) {
    unsigned int b = __float_as_uint(v);
    return (b & 0x80000000u) ? ~b : (b | 0x80000000u);
}
__device__ __forceinline__ float fkey_inv(unsigned int key) {
    unsigned int b = (key & 0x80000000u) ? (key ^ 0x80000000u) : ~key;
    return __uint_as_float(b);
}

__device__ __forceinline__ void st_agent(float* p, float v) {
    __hip_atomic_store(p, v, __ATOMIC_RELAXED, __HIP_MEMORY_SCOPE_AGENT);  // sc1 write-through
}
__device__ __forceinline__ float ld_agent(const float* p) {
    return __hip_atomic_load(p, __ATOMIC_RELAXED, __HIP_MEMORY_SCOPE_AGENT);  // sc1 load
}

// ---------------- Kernel 1: argmin(usages) (single block) ----------------
__global__ __launch_bounds__(1024) void k_argmin(const float* __restrict__ usages,
                                                 float* __restrict__ W) {
    __shared__ u64 s[16];
    const int t = threadIdx.x;
    if (t == 0) { ((int*)W)[0] = 0; ((int*)W)[1] = 0; }  // boundary flush publishes
    u64 best = ~0ULL;
    #pragma unroll
    for (int i = 0; i < KP / 1024; i++) {
        const int j = t + i * 1024;
        u64 p = ((u64)fkey(usages[j]) << 32) | (unsigned int)j;
        if (p < best) best = p;  // min; equal key -> smaller j (first occurrence)
    }
    #pragma unroll
    for (int m = 32; m >= 1; m >>= 1) {
        u64 o = __shfl_xor(best, m, 64);
        if (o < best) best = o;
    }
    if ((t & 63) == 0) s[t >> 6] = best;
    __syncthreads();
    if (t < 64) {
        best = s[t & 15];
        #pragma unroll
        for (int m = 8; m >= 1; m >>= 1) {
            u64 o = __shfl_xor(best, m, 64);
            if (o < best) best = o;
        }
        if (t == 0) ((int*)W)[2] = (int)(best & 0xFFFFFFFFu);
    }
}

// ---- Kernel 2: fused dots + speculative evict copy + fence-free scalar tail ----
// Memory path: R3-identical (nt loads on P; reg-shuffle +3-shift nt stores).
// Tail: last block (relaxed atomicAdd gate) emulates R3's 1024-thread k_scalar
// with 256 threads x 4 virtual threads. Sum trees are fixed DAGs with barriers
// between levels -> bit-identical; max/argmax are order-free.
__global__ __launch_bounds__(256) void k_dots_copy(const float* __restrict__ z,
                                                   const float* __restrict__ P,
                                                   const float* __restrict__ usages,
                                                   const float* __restrict__ beta,
                                                   const float* __restrict__ gamma,
                                                   const float* __restrict__ temp,
                                                   float* __restrict__ W,
                                                   float* __restrict__ out) {
    __shared__ float sf[1024];
    __shared__ float sm[4];
    __shared__ u64 sb[4];
    __shared__ int isLast;
    const int wave = threadIdx.x >> 6;
    const int lane = threadIdx.x & 63;
    const int r = blockIdx.x * 4 + wave;
    const int idx = ((const int*)W)[2];

    const float* prow = P + (size_t)r * DP;

    f4 v[8];
    float zp = 0.f, pp = 0.f, zz = 0.f;
    #pragma unroll
    for (int i = 0; i < 8; i++) {
        const int c = i * 256 + lane * 4;
        const f4 pv = __builtin_nontemporal_load((const f4*)(prow + c));
        const f4 zv = *(const f4*)(z + c);
        v[i] = pv;
        zp += pv.x * zv.x + pv.y * zv.y + pv.z * zv.z + pv.w * zv.w;
        pp += pv.x * pv.x + pv.y * pv.y + pv.z * pv.z + pv.w * pv.w;
        zz += zv.x * zv.x + zv.y * zv.y + zv.z * zv.z + zv.w * zv.w;
    }

    // Speculative evict-layout copy: in-row r -> out-row (r<idx ? r : r-1).
    if (r != idx) {
        const int ro = (r < idx) ? r : r - 1;
        float* orow = out + 3 + (size_t)ro * DP;
        if (lane == 0) __builtin_nontemporal_store(v[0].x, orow);
        #pragma unroll
        for (int i = 0; i < 8; i++) {
            float nx = __shfl_down(v[i].x, 1);
            const float bx = __shfl(v[(i + 1) & 7].x, 0);
            if (lane == 63) nx = bx;
            f4 ov;
            ov.x = v[i].y; ov.y = v[i].z; ov.z = v[i].w; ov.w = nx;
            if (i < 7 || lane < 63) {
                __builtin_nontemporal_store(ov, (f4*)(orow + 1 + 4 * (i * 64 + lane)));
            }
        }
        if (lane == 63) {
            f2 t2; t2.x = v[7].y; t2.y = v[7].z;
            __builtin_nontemporal_store(t2, (f2*)(orow + DP - 3));
            __builtin_nontemporal_store(v[7].w, orow + DP - 1);
        }
    }

    zp = waveReduceSum(zp);
    pp = waveReduceSum(pp);
    zz = waveReduceSum(zz);
    if (lane == 0) {
        st_agent(&W[8 + r], temp[0] * zp / sqrtf(zz * pp));  // logit: sc1 for tail
        W[8 + KP + r]     = zp;   // consumed by k_ema (next dispatch) -> boundary flush
        W[8 + 2 * KP + r] = pp;
        if (r == 0) W[7] = zz;
    }

    // ---------------- fence-free completion gate ----------------
    asm volatile("s_waitcnt vmcnt(0)" ::: "memory");  // per-wave: sc1 stores now at MALL
    __syncthreads();
    if (threadIdx.x == 0) isLast = (atomicAdd((int*)W, 1) == GRID_DOTS - 1);
    __syncthreads();
    if (!isLast) return;

    // -------- scalar tail: 256 threads emulate k_scalar's 1024-thread body --------
    const int tp = threadIdx.x;  // t' in [0,256)
    // Phase A: mx_all (all j) + bestx (excluding idx). Order-free.
    float mx_all = -INFINITY;
    u64 bestx = 0;
    #pragma unroll
    for (int k = 0; k < 4; k++) {
        #pragma unroll
        for (int i = 0; i < KP / 1024; i++) {
            const int j = tp + k * 256 + i * 1024;
            const float vv = ld_agent(&W[8 + j]);
            mx_all = fmaxf(mx_all, vv);
            if (j != idx) {
                u64 p = ((u64)fkey(vv) << 32) | (unsigned int)(~j);
                if (p > bestx) bestx = p;
            }
        }
    }
    #pragma unroll
    for (int m = 32; m >= 1; m >>= 1) {
        mx_all = fmaxf(mx_all, __shfl_xor(mx_all, m, 64));
        u64 o = __shfl_xor(bestx, m, 64);
        if (o > bestx) bestx = o;
    }
    if (lane == 0) { sm[wave] = mx_all; sb[wave] = bestx; }
    __syncthreads();
    if (tp < 64) {  // one wave; values repeat every 4 lanes
        float m = sm[tp & 3];
        u64 b = sb[tp & 3];
        #pragma unroll
        for (int mk = 2; mk >= 1; mk >>= 1) {
            m = fmaxf(m, __shfl_xor(m, mk, 64));
            u64 o = __shfl_xor(b, mk, 64);
            if (o > b) b = o;
        }
        if (tp == 0) { sm[0] = m; sb[0] = b; }
    }
    __syncthreads();
    mx_all = sm[0];

    const float u = 1.f / (1.f + expf(-((-mx_all - beta[0]) / gamma[0])));
    const int flag = (u >= THRESH) ? 1 : 0;
    if (tp == 0) {
        out[2] = u;
        ((int*)W)[3] = flag;  // read by k_ema next dispatch (boundary flush)
        W[4] = mx_all;
        W[6] = u;
    }

    if (flag) {
        // ---------- evict epilogue ----------
        const u64 bp = sb[0];
        const float mxe = fkey_inv((unsigned int)(bp >> 32));
        const int amax = (int)(~(unsigned int)(bp & 0xFFFFFFFFu));
        const float tq = temp[0];
        const float M2 = fmaxf(mxe, tq);
        // per-virtual-thread sums, i ascending (bit-identical to R3 thread t)
        #pragma unroll
        for (int k = 0; k < 4; k++) {
            const int t = tp + k * 256;
            float s = 0.f;
            #pragma unroll
            for (int i = 0; i < KP / 1024; i++) {
                const int j = t + i * 1024;
                if (j != idx) s += expf(ld_agent(&W[8 + j]) - M2);
            }
            sf[t] = s;
        }
        __syncthreads();
        // 1024-leaf pairwise tree, levels barrier-separated (fixed DAG -> bit-exact)
        for (int off = 512; off >= 1; off >>= 1) {
            for (int tt = tp; tt < off; tt += 256) sf[tt] += sf[tt + off];
            __syncthreads();
        }
        if (tp == 0) {
            const float total = sf[0] + expf(tq - M2);
            out[0] = logf(total);  // loss = logsumexp(l2) - max(l2); l2[label]==max
            const int label = (mxe >= tq) ? (amax < idx ? amax : amax - 1) : (KP - 1);
            out[1] = (float)label;
        }
        // new_usages = [usages[src]; 1.0] * DECAY
        float* ou = out + 3 + (size_t)KP * DP;
        #pragma unroll
        for (int k = 0; k < 4; k++) {
            #pragma unroll
            for (int i = 0; i < KP / 1024; i++) {
                const int j = tp + k * 256 + i * 1024;
                ou[j] = (j < KP - 1) ? usages[j < idx ? j : j + 1] * DECAY : DECAY;
            }
        }
        // new_protos last row = z
        float* orow = out + 3 + (size_t)(KP - 1) * DP;
        #pragma unroll
        for (int k = 0; k < 8; k++) orow[tp + k * 256] = z[tp + k * 256];
    } else {
        // ---------- ema prep: softmax denominator (all j, incl idx) ----------
        #pragma unroll
        for (int k = 0; k < 4; k++) {
            const int t = tp + k * 256;
            float s = 0.f;
            #pragma unroll
            for (int i = 0; i < KP / 1024; i++) s += expf(ld_agent(&W[8 + t + i * 1024]) - mx_all);
            sf[t] = s;
        }
        __syncthreads();
        for (int off = 512; off >= 1; off >>= 1) {
            for (int tt = tp; tt < off; tt += 256) sf[tt] += sf[tt + off];
            __syncthreads();
        }
        if (tp == 0) W[5] = sf[0];
    }
}

// --------- Kernel 3: EMA rewrite + fence-free loss tail (stub on evict path) ---------
__global__ __launch_bounds__(256) void k_ema(const float* __restrict__ z,
                                             const float* __restrict__ P,
                                             const float* __restrict__ usages,
                                             const float* __restrict__ temp,
                                             float* __restrict__ W,
                                             float* __restrict__ out) {
    if (((const int*)W)[3]) return;  // evict branch taken -> nothing to do
    __shared__ float sf[1024];
    __shared__ float sm[4];
    __shared__ u64 sb[4];
    __shared__ int isLast;
    const int wave = threadIdx.x >> 6;
    const int lane = threadIdx.x & 63;
    const int r = blockIdx.x * 4 + wave;

    const float mx = W[4], se = W[5], u = W[6], zz = W[7];
    const float lg = W[8 + r], zp = W[8 + KP + r], pp = W[8 + 2 * KP + r];
    const float y = expf(lg - mx) / se;
    const float delta = y * (1.f - u);
    const float usg = usages[r];
    const float a = delta / (delta + usg);
    const float b = usg / (usg + delta);

    const float* prow = P + (size_t)r * DP;
    float* orow = out + 3 + (size_t)r * DP;
    f4 v[8];
    #pragma unroll
    for (int i = 0; i < 8; i++) {
        const int c = i * 256 + lane * 4;
        const f4 pv = *(const f4*)(prow + c);
        const f4 zv = *(const f4*)(z + c);
        f4 ov;
        ov.x = a * zv.x + b * pv.x;
        ov.y = a * zv.y + b * pv.y;
        ov.z = a * zv.z + b * pv.z;
        ov.w = a * zv.w + b * pv.w;
        v[i] = ov;
    }
    if (lane == 0) __builtin_nontemporal_store(v[0].x, orow);
    #pragma unroll
    for (int i = 0; i < 8; i++) {
        float nx = __shfl_down(v[i].x, 1);
        const float bx = __shfl(v[(i + 1) & 7].x, 0);
        if (lane == 63) nx = bx;
        f4 ov;
        ov.x = v[i].y; ov.y = v[i].z; ov.z = v[i].w; ov.w = nx;
        if (i < 7 || lane < 63) {
            __builtin_nontemporal_store(ov, (f4*)(orow + 1 + 4 * (i * 64 + lane)));
        }
    }
    if (lane == 63) {
        f2 t2; t2.x = v[7].y; t2.y = v[7].z;
        __builtin_nontemporal_store(t2, (f2*)(orow + DP - 3));
        __builtin_nontemporal_store(v[7].w, orow + DP - 1);
    }

    if (lane == 0) {
        const float dzn = a * zz + b * zp;
        const float n2 = a * a * zz + 2.f * a * b * zp + b * b * pp;
        st_agent(&W[8 + 3 * KP + r], temp[0] * dzn / sqrtf(zz * n2));  // sc1 for tail
        out[3 + (size_t)KP * DP + r] = (usg + delta) * DECAY;
    }

    // ---------------- fence-free completion gate ----------------
    asm volatile("s_waitcnt vmcnt(0)" ::: "memory");
    __syncthreads();
    if (threadIdx.x == 0) isLast = (atomicAdd((int*)W + 1, 1) == GRID_DOTS - 1);
    __syncthreads();
    if (!isLast) return;

    // -------- loss tail: 256 threads emulate k_ema_loss's 1024-thread body --------
    const int tp = threadIdx.x;
    u64 best = 0;  // order-free argmax (packed key, smaller j wins on tie)
    #pragma unroll
    for (int k = 0; k < 4; k++) {
        #pragma unroll
        for (int i = 0; i < KP / 1024; i++) {
            const int j = tp + k * 256 + i * 1024;
            const float vv = ld_agent(&W[8 + 3 * KP + j]);
            u64 p = ((u64)fkey(vv) << 32) | (unsigned int)(~j);
            if (p > best) best = p;
        }
    }
    #pragma unroll
    for (int m = 32; m >= 1; m >>= 1) {
        u64 o = __shfl_xor(best, m, 64);
        if (o > best) best = o;
    }
    if (lane == 0) sb[wave] = best;
    __syncthreads();
    if (tp < 64) {
        u64 b = sb[tp & 3];
        #pragma unroll
        for (int mk = 2; mk >= 1; mk >>= 1) {
            u64 o = __shfl_xor(b, mk, 64);
            if (o > b) b = o;
        }
        if (tp == 0) sb[0] = b;
    }
    __syncthreads();
    const u64 bp = sb[0];
    const float mxl = fkey_inv((unsigned int)(bp >> 32));
    const int label = (int)(~(unsigned int)(bp & 0xFFFFFFFFu));

    #pragma unroll
    for (int k = 0; k < 4; k++) {
        const int t = tp + k * 256;
        float s = 0.f;
        #pragma unroll
        for (int i = 0; i < KP / 1024; i++) s += expf(ld_agent(&W[8 + 3 * KP + t + i * 1024]) - mxl);
        sf[t] = s;
    }
    __syncthreads();
    for (int off = 512; off >= 1; off >>= 1) {
        for (int tt = tp; tt < off; tt += 256) sf[tt] += sf[tt + off];
        __syncthreads();
    }
    if (tp == 0) {
        out[0] = logf(sf[0]);  // l2[label] == mxl
        out[1] = (float)label;
    }
}

extern "C" void kernel_launch(void* const* d_in, const int* in_sizes, int n_in,
                              void* d_out, int out_size, void* d_ws, size_t ws_size,
                              hipStream_t stream) {
    const float* z      = (const float*)d_in[0];
    const float* P      = (const float*)d_in[1];
    const float* usages = (const float*)d_in[2];
    const float* beta   = (const float*)d_in[3];
    const float* gamma  = (const float*)d_in[4];
    const float* temp   = (const float*)d_in[5];
    float* out = (float*)d_out;
    float* W   = (float*)d_ws;  // needs (8 + 4*KP)*4 = 262176 bytes

    k_argmin<<<1, 1024, 0, stream>>>(usages, W);
    k_dots_copy<<<GRID_DOTS, 256, 0, stream>>>(z, P, usages, beta, gamma, temp, W, out);
    k_ema<<<GRID_DOTS, 256, 0, stream>>>(z, P, usages, temp, W, out);
}